// Round 7
// baseline (333.104 us; speedup 1.0000x reference)
//
#include <hip/hip_runtime.h>
#include <hip/hip_cooperative_groups.h>
#include <math.h>

namespace cg = cooperative_groups;

static constexpr int Dd   = 128;
static constexpr int NH   = 8;
static constexpr int NE   = 256;
static constexpr int TT   = 512;
static constexpr int NTOK = 2048;
static constexpr int SLOTS = 256;
#define EPSF 1e-6f

__device__ __forceinline__ float elu1(float v) { return v > 0.f ? v + 1.f : expf(v); }
__device__ __forceinline__ float sigm(float v) { return 1.f / (1.f + expf(-v)); }

// One cooperative kernel: 256 blocks x 512 threads (1 block/CU guaranteed
// co-resident -> cooperative launch always legal). Block b owns tokens
// 8b..8b+7. Phases: init -> pre -> ctx -> mid -> exp -> post (5 grid.sync).
__global__ __launch_bounds__(512, 2) void k_all(
    const float* __restrict__ x, const float* __restrict__ g1,
    const float* __restrict__ qW, const float* __restrict__ qb,
    const float* __restrict__ kdW, const float* __restrict__ kdb,
    const float* __restrict__ kuW, const float* __restrict__ kub,
    const float* __restrict__ oW, const float* __restrict__ ob,
    const float* __restrict__ rot, const float* __restrict__ tqs,
    const float* __restrict__ s1W, const float* __restrict__ s1b,
    const float* __restrict__ s2W, const float* __restrict__ s2b,
    const float* __restrict__ g2, const float* __restrict__ gateW,
    const float* __restrict__ gateb, const float* __restrict__ expW,
    const float* __restrict__ m1W, const float* __restrict__ m1b,
    const float* __restrict__ m2W, const float* __restrict__ m2b,
    float* __restrict__ kvbuf, float* __restrict__ ctx, float* __restrict__ ksum,
    float* __restrict__ h2buf, float* __restrict__ oR, float* __restrict__ bR,
    float* __restrict__ kvW, float* __restrict__ bkv,
    int* __restrict__ cnt, int* __restrict__ slottok,
    float* __restrict__ ybuf, float* __restrict__ out) {
  cg::grid_group grid = cg::this_grid();
  const int blk = blockIdx.x, tid = threadIdx.x;
  const int lane = tid & 63;
  const int n0 = blk * 8;

  // scratch sm[0..7183]; persistent qT 7184..8207, xnT 8208..9231
  __shared__ __align__(16) float sm[9232];
  float* qT  = sm + 7184;  // [128][8]
  float* xnT = sm + 8208;  // [128][8]
  __shared__ float wvS[4][8]; __shared__ int wiS[4][8]; __shared__ float zS[4][8];
  __shared__ float sWt[8][2]; __shared__ int sSlot[8][2];

  // ---------------- phase 0: init -------------------------------------------
  if (blk < 32) {                       // oR = oW @ rot (128x128, K=128)
    int idx = blk * 512 + tid;
    int row = idx >> 7, col = idx & 127;
    const float* ow = oW + row * 128;
    float acc = 0.f;
#pragma unroll 8
    for (int k = 0; k < 128; k++) acc += ow[k] * rot[k * 128 + col];
    oR[row * 128 + col] = acc;
  } else if (blk == 32) {               // bR, bkv
    if (tid < 128) {
      float acc = 0.f;
#pragma unroll 8
      for (int k = 0; k < 128; k++) acc += ob[k] * rot[k * 128 + tid];
      bR[tid] = acc;
    }
    if (tid < 256) {
      float acc = kub[tid];
#pragma unroll
      for (int k = 0; k < 32; k++) acc += kdb[k] * kuW[k * 256 + tid];
      bkv[tid] = acc;
    }
  } else if (blk == 33) {               // zero ctx/ksum/cnt
    for (int i = tid; i < 32 * 256; i += 512) ctx[i] = 0.f;
    ksum[tid] = 0.f;
    if (tid < 256) cnt[tid] = 0;
  } else if (blk >= 34 && blk < 98) {   // kvW = kdW @ kuW (128x256, K=32)
    int idx = (blk - 34) * 512 + tid;
    int row = idx >> 8, col = idx & 255;
    const float* kw = kdW + row * 32;
    float acc = 0.f;
#pragma unroll
    for (int k = 0; k < 32; k++) acc += kw[k] * kuW[k * 256 + col];
    kvW[row * 256 + col] = acc;
  }
  grid.sync();

  // ---------------- phase 1: pre --------------------------------------------
  {
    float* xgT   = sm;          // [128][8]
    float* qpart = sm + 1024;   // [128][8]
    float* rtmp  = sm + 2048;   // [2][8]
    if (tid < 128) {
      float g1j = g1[tid];
      float v[8];
#pragma unroll
      for (int t = 0; t < 8; t++) {
        float xv = x[(n0 + t) * Dd + tid];
        v[t] = xv * xv;
        xgT[tid * 8 + t] = xv * g1j;
      }
#pragma unroll
      for (int o = 32; o > 0; o >>= 1) {
#pragma unroll
        for (int t = 0; t < 8; t++) v[t] += __shfl_xor(v[t], o, 64);
      }
      if (lane == 0) {
#pragma unroll
        for (int t = 0; t < 8; t++) rtmp[(tid >> 6) * 8 + t] = v[t];
      }
    }
    __syncthreads();

    float acc[8] = {0, 0, 0, 0, 0, 0, 0, 0};
    if (tid < 256) {                    // q GEMV, K-split-2
      int j = tid & 127, kh = tid >> 7;
      const float* Wp = qW + (kh * 64) * Dd + j;
      const float* hb = xgT + (kh * 64) * 8;
#pragma unroll 8
      for (int i = 0; i < 64; i++) {
        float w = Wp[i * Dd];
        float4 A = *(const float4*)(hb + i * 8);
        float4 B = *(const float4*)(hb + i * 8 + 4);
        acc[0] += A.x * w; acc[1] += A.y * w; acc[2] += A.z * w; acc[3] += A.w * w;
        acc[4] += B.x * w; acc[5] += B.y * w; acc[6] += B.z * w; acc[7] += B.w * w;
      }
      if (kh) {
        *(float4*)(qpart + j * 8)     = make_float4(acc[0], acc[1], acc[2], acc[3]);
        *(float4*)(qpart + j * 8 + 4) = make_float4(acc[4], acc[5], acc[6], acc[7]);
      }
    } else {                            // kv GEMV, 256 cols, K=128
      int col = tid - 256;
      const float* Wp = kvW + col;
#pragma unroll 8
      for (int i = 0; i < 128; i++) {
        float w = Wp[i * 256];
        float4 A = *(const float4*)(xgT + i * 8);
        float4 B = *(const float4*)(xgT + i * 8 + 4);
        acc[0] += A.x * w; acc[1] += A.y * w; acc[2] += A.z * w; acc[3] += A.w * w;
        acc[4] += B.x * w; acc[5] += B.y * w; acc[6] += B.z * w; acc[7] += B.w * w;
      }
    }
    __syncthreads();

    float r[8];
#pragma unroll
    for (int t = 0; t < 8; t++)
      r[t] = rsqrtf((rtmp[t] + rtmp[8 + t]) * (1.f / 128.f) + EPSF);
    if (tid < 128) {
      float bb = qb[tid];
#pragma unroll
      for (int t = 0; t < 8; t++)
        qT[tid * 8 + t] = elu1((acc[t] + qpart[tid * 8 + t]) * r[t] + bb);
    } else if (tid >= 256) {
      int col = tid - 256;
      float bb = bkv[col];
      bool isk = (col & 31) < 16;
#pragma unroll
      for (int t = 0; t < 8; t++) {
        float v = acc[t] * r[t] + bb;
        kvbuf[(n0 + t) * 256 + col] = isk ? elu1(v) : v;
      }
    }
  }
  grid.sync();

  // ---------------- phase 2: ctx (32 bh x 8 chunks of 64 tokens) ------------
  {
    float* sh = sm;                     // 2048 floats
    int bh = blk >> 3, c = blk & 7;
    int b = bh >> 3, h = bh & 7;
#pragma unroll
    for (int r = 0; r < 4; r++) {
      int lin = r * 512 + tid;
      int tok = lin >> 5, off = lin & 31;
      sh[lin] = kvbuf[((b * TT + c * 64 + tok) * 256) + h * 32 + off];
    }
    __syncthreads();
    if (tid < 256) {
      int d = tid >> 4, e = tid & 15;
      float acc = 0.f, ks = 0.f;
#pragma unroll 4
      for (int t = 0; t < 64; t++) {
        float kk = sh[t * 32 + d];
        acc += kk * sh[t * 32 + 16 + e];
        ks += kk;
      }
      atomicAdd(&ctx[bh * 256 + d * 16 + e], acc);
      if (e == 0) atomicAdd(&ksum[bh * 16 + d], ks);
    }
  }
  grid.sync();

  // ---------------- phase 3: mid --------------------------------------------
  {
    float* bufA  = sm;          // [128][8]
    float* bufB  = sm + 1024;   // [128][8]
    float* part  = sm + 2048;   // 3*[128][8]
    float* gpart = sm + 5120;   // [256][8]
    float* rtmp  = sm + 7168;   // [2][8]
    const int j = tid & 127, g = tid >> 7;

    float xres[8];
    if (tid < 128) {
#pragma unroll
      for (int t = 0; t < 8; t++) xres[t] = x[(n0 + t) * Dd + j];
    }
    // attention apply on qT -> bufB
    if (tid < 128) {
      int h = j >> 4, e = j & 15;
      const float* cpt = ctx + ((n0 >> 9) * NH + h) * 256;
      const float* kpt = ksum + ((n0 >> 9) * NH + h) * 16;
      float num[8] = {0, 0, 0, 0, 0, 0, 0, 0}, den[8] = {0, 0, 0, 0, 0, 0, 0, 0};
#pragma unroll
      for (int d = 0; d < 16; d++) {
        float cx = cpt[d * 16 + e], ks = kpt[d];
        const float* q8 = qT + (h * 16 + d) * 8;
#pragma unroll
        for (int t = 0; t < 8; t++) { float qd = q8[t]; num[t] += qd * cx; den[t] += qd * ks; }
      }
#pragma unroll
      for (int t = 0; t < 8; t++) bufB[j * 8 + t] = num[t] / (den[t] + EPSF);
    }
    __syncthreads();

    // z = bufB @ oR + bR; quant -> bufA (K-split-4)
    {
      float acc[8] = {0, 0, 0, 0, 0, 0, 0, 0};
      const float* Wp = oR + (g * 32) * Dd + j;
      const float* hb = bufB + (g * 32) * 8;
#pragma unroll 8
      for (int i = 0; i < 32; i++) {
        float w = Wp[i * Dd];
        float4 A = *(const float4*)(hb + i * 8);
        float4 B = *(const float4*)(hb + i * 8 + 4);
        acc[0] += A.x * w; acc[1] += A.y * w; acc[2] += A.z * w; acc[3] += A.w * w;
        acc[4] += B.x * w; acc[5] += B.y * w; acc[6] += B.z * w; acc[7] += B.w * w;
      }
      if (g) {
        *(float4*)(part + (g - 1) * 1024 + j * 8)     = make_float4(acc[0], acc[1], acc[2], acc[3]);
        *(float4*)(part + (g - 1) * 1024 + j * 8 + 4) = make_float4(acc[4], acc[5], acc[6], acc[7]);
      }
      __syncthreads();
      float tot[8];
      if (g == 0) {
        float bb = bR[j];
        float v[8];
#pragma unroll
        for (int t = 0; t < 8; t++) {
          tot[t] = acc[t] + part[j * 8 + t] + part[1024 + j * 8 + t] + part[2048 + j * 8 + t] + bb;
          v[t] = tot[t] * tot[t];
        }
#pragma unroll
        for (int o = 32; o > 0; o >>= 1) {
#pragma unroll
          for (int t = 0; t < 8; t++) v[t] += __shfl_xor(v[t], o, 64);
        }
        if (lane == 0) {
#pragma unroll
          for (int t = 0; t < 8; t++) rtmp[(tid >> 6) * 8 + t] = v[t];
        }
      }
      __syncthreads();
      if (g == 0) {
        float scj = tqs[j];
#pragma unroll
        for (int t = 0; t < 8; t++) {
          float mag = sqrtf((rtmp[t] + rtmp[8 + t]) * (1.f / 128.f) + EPSF);
          float zc = fminf(fmaxf(tot[t], -mag), mag);
          bufA[j * 8 + t] = zc * scj;
        }
      }
      __syncthreads();
    }

    // s1/s2 dual GEMV -> xn(+res) -> xnT; bufB = g2*xn
    {
      float acc[8] = {0, 0, 0, 0, 0, 0, 0, 0};
      const float* Wp = (g < 2 ? s1W : s2W) + ((g & 1) * 64) * Dd + j;
      const float* hb = bufA + ((g & 1) * 64) * 8;
#pragma unroll 8
      for (int i = 0; i < 64; i++) {
        float w = Wp[i * Dd];
        float4 A = *(const float4*)(hb + i * 8);
        float4 B = *(const float4*)(hb + i * 8 + 4);
        acc[0] += A.x * w; acc[1] += A.y * w; acc[2] += A.z * w; acc[3] += A.w * w;
        acc[4] += B.x * w; acc[5] += B.y * w; acc[6] += B.z * w; acc[7] += B.w * w;
      }
      if (g) {
        *(float4*)(part + (g - 1) * 1024 + j * 8)     = make_float4(acc[0], acc[1], acc[2], acc[3]);
        *(float4*)(part + (g - 1) * 1024 + j * 8 + 4) = make_float4(acc[4], acc[5], acc[6], acc[7]);
      }
      __syncthreads();
      if (g == 0) {
        float b1 = s1b[j], b2 = s2b[j], g2j = g2[j];
        float v[8];
#pragma unroll
        for (int t = 0; t < 8; t++) {
          float gv = acc[t] + part[j * 8 + t] + b1;
          float uv = part[1024 + j * 8 + t] + part[2048 + j * 8 + t] + b2;
          float xn = xres[t] + gv * sigm(gv) * uv;
          xnT[j * 8 + t] = xn;
          bufB[j * 8 + t] = g2j * xn;
          v[t] = xn * xn;
        }
#pragma unroll
        for (int o = 32; o > 0; o >>= 1) {
#pragma unroll
          for (int t = 0; t < 8; t++) v[t] += __shfl_xor(v[t], o, 64);
        }
        if (lane == 0) {
#pragma unroll
          for (int t = 0; t < 8; t++) rtmp[(tid >> 6) * 8 + t] = v[t];
        }
      }
      __syncthreads();
    }

    // gate logits (256 cols, K-split-2); r2 applied at epilogue
    float val[8], r2[8];
    {
      int col = tid & 255, kh = tid >> 8;
      float acc[8] = {0, 0, 0, 0, 0, 0, 0, 0};
      const float* Wp = gateW + (kh * 64) * NE + col;
      const float* hb = bufB + (kh * 64) * 8;
#pragma unroll 8
      for (int i = 0; i < 64; i++) {
        float w = Wp[i * NE];
        float4 A = *(const float4*)(hb + i * 8);
        float4 B = *(const float4*)(hb + i * 8 + 4);
        acc[0] += A.x * w; acc[1] += A.y * w; acc[2] += A.z * w; acc[3] += A.w * w;
        acc[4] += B.x * w; acc[5] += B.y * w; acc[6] += B.z * w; acc[7] += B.w * w;
      }
      if (kh) {
        *(float4*)(gpart + col * 8)     = make_float4(acc[0], acc[1], acc[2], acc[3]);
        *(float4*)(gpart + col * 8 + 4) = make_float4(acc[4], acc[5], acc[6], acc[7]);
      }
      __syncthreads();
#pragma unroll
      for (int t = 0; t < 8; t++)
        r2[t] = rsqrtf((rtmp[t] + rtmp[8 + t]) * (1.f / 128.f) + EPSF);
      if (!kh) {
        float bb = gateb[col];
#pragma unroll
        for (int t = 0; t < 8; t++) val[t] = (acc[t] + gpart[col * 8 + t]) * r2[t] + bb;
      }
      if (tid < 128) {
#pragma unroll
        for (int t = 0; t < 8; t++)
          h2buf[(n0 + t) * Dd + j] = bufB[j * 8 + t] * r2[t];
      }
    }
    __syncthreads();

    // top-2 + softmax + scatter
    float m1[8]; int i1[8];
    if (tid < 256) {
      float bv[8]; int bi[8];
#pragma unroll
      for (int t = 0; t < 8; t++) { bv[t] = val[t]; bi[t] = tid; }
#pragma unroll
      for (int o = 32; o > 0; o >>= 1) {
#pragma unroll
        for (int t = 0; t < 8; t++) {
          float wv = __shfl_xor(bv[t], o, 64);
          int wi = __shfl_xor(bi[t], o, 64);
          if (wv > bv[t] || (wv == bv[t] && wi < bi[t])) { bv[t] = wv; bi[t] = wi; }
        }
      }
      if (lane == 0) {
#pragma unroll
        for (int t = 0; t < 8; t++) { wvS[tid >> 6][t] = bv[t]; wiS[tid >> 6][t] = bi[t]; }
      }
    }
    __syncthreads();
    if (tid < 256) {
#pragma unroll
      for (int t = 0; t < 8; t++) {
        m1[t] = wvS[0][t]; i1[t] = wiS[0][t];
#pragma unroll
        for (int w = 1; w < 4; w++) {
          float cv = wvS[w][t]; int ci = wiS[w][t];
          if (cv > m1[t] || (cv == m1[t] && ci < i1[t])) { m1[t] = cv; i1[t] = ci; }
        }
      }
    }
    __syncthreads();
    float m2[8]; int i2[8];
    if (tid < 256) {
      float bv[8]; int bi[8];
#pragma unroll
      for (int t = 0; t < 8; t++) {
        bv[t] = (tid == i1[t]) ? -INFINITY : val[t];
        bi[t] = tid;
      }
#pragma unroll
      for (int o = 32; o > 0; o >>= 1) {
#pragma unroll
        for (int t = 0; t < 8; t++) {
          float wv = __shfl_xor(bv[t], o, 64);
          int wi = __shfl_xor(bi[t], o, 64);
          if (wv > bv[t] || (wv == bv[t] && wi < bi[t])) { bv[t] = wv; bi[t] = wi; }
        }
      }
      if (lane == 0) {
#pragma unroll
        for (int t = 0; t < 8; t++) { wvS[tid >> 6][t] = bv[t]; wiS[tid >> 6][t] = bi[t]; }
      }
    }
    __syncthreads();
    if (tid < 256) {
#pragma unroll
      for (int t = 0; t < 8; t++) {
        m2[t] = wvS[0][t]; i2[t] = wiS[0][t];
#pragma unroll
        for (int w = 1; w < 4; w++) {
          float cv = wvS[w][t]; int ci = wiS[w][t];
          if (cv > m2[t] || (cv == m2[t] && ci < i2[t])) { m2[t] = cv; i2[t] = ci; }
        }
      }
    }
    __syncthreads();
    if (tid < 256) {
      float v[8];
#pragma unroll
      for (int t = 0; t < 8; t++) v[t] = expf(val[t] - m1[t]);
#pragma unroll
      for (int o = 32; o > 0; o >>= 1) {
#pragma unroll
        for (int t = 0; t < 8; t++) v[t] += __shfl_xor(v[t], o, 64);
      }
      if (lane == 0) {
#pragma unroll
        for (int t = 0; t < 8; t++) zS[tid >> 6][t] = v[t];
      }
    }
    __syncthreads();
    if (tid < 8) {
      int t = tid, tok = n0 + t;
      float Z = zS[0][t] + zS[1][t] + zS[2][t] + zS[3][t];
      float p1 = 1.f / Z;
      float p2 = expf(m2[t] - m1[t]) / Z;
      float s = p1 + p2 + EPSF;
      int e1 = i1[t], e2 = i2[t];
      int s1 = atomicAdd(&cnt[e1], 1); if (s1 > SLOTS - 1) s1 = SLOTS - 1;
      int s2 = atomicAdd(&cnt[e2], 1); if (s2 > SLOTS - 1) s2 = SLOTS - 1;
      int sl1 = e1 * SLOTS + s1, sl2 = e2 * SLOTS + s2;
      slottok[sl1] = tok; slottok[sl2] = tok;
      sSlot[t][0] = sl1; sSlot[t][1] = sl2;
      sWt[t][0] = p1 / s; sWt[t][1] = p2 / s;
    }
  }
  grid.sync();

  // ---------------- phase 4: exp (1 block per expert) -----------------------
  {
    int e = blk;
    int n = cnt[e]; if (n > SLOTS) n = SLOTS;
    int base = e * SLOTS;
    const int j = tid & 127, g = tid >> 7;
    float* hT = sm;                     // 128*20 floats
    const float* Wp = expW + (size_t)e * Dd * Dd + j;
    for (int t0 = 0; t0 < n; t0 += 16) {
      int m = n - t0; if (m > 16) m = 16;
      __syncthreads();
      for (int tt = g; tt < m; tt += 4) {
        int tok = slottok[base + t0 + tt];
        hT[j * 20 + tt] = h2buf[tok * Dd + j];
      }
      __syncthreads();
      float acc[4] = {0, 0, 0, 0};
#pragma unroll 8
      for (int i = 0; i < 128; i++) {
        float w = Wp[i * Dd];
        float4 h4 = *(const float4*)&hT[i * 20 + g * 4];
        acc[0] += h4.x * w; acc[1] += h4.y * w; acc[2] += h4.z * w; acc[3] += h4.w * w;
      }
#pragma unroll
      for (int k = 0; k < 4; k++) {
        int tt = g * 4 + k;
        if (tt < m) ybuf[(size_t)(base + t0 + tt) * Dd + j] = acc[k];
      }
    }
  }
  grid.sync();

  // ---------------- phase 5: post -------------------------------------------
  {
    float* y1T  = sm;           // [128][8]
    float* y2T  = sm + 1024;
    float* inT  = sm + 2048;
    float* sT   = sm + 3072;
    float* part = sm + 4096;    // 3*[128][8]
    float* rtmp = sm + 7168;    // [2][8]
    const int j = tid & 127, g = tid >> 7;

#pragma unroll
    for (int tt = 0; tt < 2; tt++) {
      int t = g * 2 + tt;
      float y1 = ybuf[(size_t)sSlot[t][0] * Dd + j];
      float y2 = ybuf[(size_t)sSlot[t][1] * Dd + j];
      y1T[j * 8 + t] = y1;
      y2T[j * 8 + t] = y2;
      inT[j * 8 + t] = sWt[t][0] * y1 + sWt[t][1] * y2;
    }
    __syncthreads();

    {
      float acc[8] = {0, 0, 0, 0, 0, 0, 0, 0};
      const float* Wp = (g < 2 ? m1W : m2W) + ((g & 1) * 64) * Dd + j;
      const float* hb = inT + ((g & 1) * 64) * 8;
#pragma unroll 8
      for (int i = 0; i < 64; i++) {
        float w = Wp[i * Dd];
        float4 A = *(const float4*)(hb + i * 8);
        float4 B = *(const float4*)(hb + i * 8 + 4);
        acc[0] += A.x * w; acc[1] += A.y * w; acc[2] += A.z * w; acc[3] += A.w * w;
        acc[4] += B.x * w; acc[5] += B.y * w; acc[6] += B.z * w; acc[7] += B.w * w;
      }
      if (g) {
        *(float4*)(part + (g - 1) * 1024 + j * 8)     = make_float4(acc[0], acc[1], acc[2], acc[3]);
        *(float4*)(part + (g - 1) * 1024 + j * 8 + 4) = make_float4(acc[4], acc[5], acc[6], acc[7]);
      }
      __syncthreads();
      if (g == 0) {
        float b1 = m1b[j], b2 = m2b[j];
#pragma unroll
        for (int t = 0; t < 8; t++) {
          float gv = acc[t] + part[j * 8 + t] + b1;
          float uv = part[1024 + j * 8 + t] + part[2048 + j * 8 + t] + b2;
          float sv = gv * sigm(gv) * uv;
          sT[j * 8 + t] = sv;
          out[(n0 + t) * Dd + j] = xnT[j * 8 + t] + sv;
        }
      }
      __syncthreads();
    }

    if (tid < 128) {
      float v[8];
#pragma unroll
      for (int t = 0; t < 8; t++) {
        float sv = sT[j * 8 + t];
        float d1 = y1T[j * 8 + t] - sv;
        float d2 = y2T[j * 8 + t] - sv;
        v[t] = sWt[t][0] * d1 * d1 + sWt[t][1] * d2 * d2;
      }
#pragma unroll
      for (int o = 32; o > 0; o >>= 1) {
#pragma unroll
        for (int t = 0; t < 8; t++) v[t] += __shfl_xor(v[t], o, 64);
      }
      if (lane == 0) {
#pragma unroll
        for (int t = 0; t < 8; t++) rtmp[(tid >> 6) * 8 + t] = v[t];
      }
    }
    __syncthreads();
    if (tid < 8) {
      float s = rtmp[tid] + rtmp[8 + tid];
      out[NTOK * Dd + n0 + tid] = expf(-s * (1.f / 128.f));
    }
  }
}

extern "C" void kernel_launch(void* const* d_in, const int* in_sizes, int n_in,
                              void* d_out, int out_size, void* d_ws, size_t ws_size,
                              hipStream_t stream) {
  const float* x   = (const float*)d_in[0];
  const float* g1  = (const float*)d_in[1];
  const float* qW  = (const float*)d_in[2];
  const float* qb  = (const float*)d_in[3];
  const float* kdW = (const float*)d_in[4];
  const float* kdb = (const float*)d_in[5];
  const float* kuW = (const float*)d_in[6];
  const float* kub = (const float*)d_in[7];
  const float* oW  = (const float*)d_in[8];
  const float* ob  = (const float*)d_in[9];
  const float* rot = (const float*)d_in[10];
  const float* tqs = (const float*)d_in[11];
  const float* s1W = (const float*)d_in[12];
  const float* s1b = (const float*)d_in[13];
  const float* s2W = (const float*)d_in[14];
  const float* s2b = (const float*)d_in[15];
  const float* g2  = (const float*)d_in[16];
  const float* gW  = (const float*)d_in[17];
  const float* gb  = (const float*)d_in[18];
  const float* eW  = (const float*)d_in[19];
  const float* m1W = (const float*)d_in[20];
  const float* m1b = (const float*)d_in[21];
  const float* m2W = (const float*)d_in[22];
  const float* m2b = (const float*)d_in[23];
  float* out = (float*)d_out;
  float* ws  = (float*)d_ws;

  float* kvbuf   = ws;                      // 524288
  float* ctx     = ws + 524288;             // 8192
  float* ksum    = ws + 532480;             // 512
  float* h2buf   = ws + 532992;             // 262144
  float* oRb     = ws + 795136;             // 16384
  float* bRb     = ws + 811520;             // 128
  float* kvW     = ws + 811648;             // 32768
  float* bkv     = ws + 844416;             // 256
  int*   cnt     = (int*)(ws + 844672);     // 256
  int*   slottok = (int*)(ws + 844928);     // 65536
  float* ybuf    = ws + 910464;             // 256*256*128

  void* args[] = {
    (void*)&x, (void*)&g1, (void*)&qW, (void*)&qb, (void*)&kdW, (void*)&kdb,
    (void*)&kuW, (void*)&kub, (void*)&oW, (void*)&ob, (void*)&rot, (void*)&tqs,
    (void*)&s1W, (void*)&s1b, (void*)&s2W, (void*)&s2b, (void*)&g2, (void*)&gW,
    (void*)&gb, (void*)&eW, (void*)&m1W, (void*)&m1b, (void*)&m2W, (void*)&m2b,
    (void*)&kvbuf, (void*)&ctx, (void*)&ksum, (void*)&h2buf, (void*)&oRb,
    (void*)&bRb, (void*)&kvW, (void*)&bkv, (void*)&cnt, (void*)&slottok,
    (void*)&ybuf, (void*)&out
  };
  hipLaunchCooperativeKernel((const void*)k_all, dim3(256), dim3(512), args, 0, stream);
}

// Round 8
// 167.243 us; speedup vs baseline: 1.9917x; 1.9917x over previous
//
#include <hip/hip_runtime.h>
#include <hip/hip_bf16.h>
#include <math.h>

static constexpr int Dd   = 128;
static constexpr int NH   = 8;
static constexpr int NE   = 256;
static constexpr int RR   = 32;
static constexpr int TT   = 512;
static constexpr int NTOK = 2048;
static constexpr int TPB  = 4;
static constexpr int SLOTS = 256;
#define EPSF 1e-6f

__device__ __forceinline__ float elu1(float v) { return v > 0.f ? v + 1.f : expf(v); }
__device__ __forceinline__ float sigm(float v) { return 1.f / (1.f + expf(-v)); }

// ===== k_pre: rmsnorm1 + q(+elu) + kd + ku(+elu on k half); zero accums =====
__global__ __launch_bounds__(512) void k_pre(
    const float* __restrict__ x, const float* __restrict__ g1,
    const float* __restrict__ qW, const float* __restrict__ qb,
    const float* __restrict__ kdW, const float* __restrict__ kdb,
    const float* __restrict__ kuW, const float* __restrict__ kub,
    float* __restrict__ qbuf, float* __restrict__ kvbuf,
    float* __restrict__ ctx, float* __restrict__ ksum, int* __restrict__ cnt) {
  const int tid = threadIdx.x;
  const int j = tid & 127, g = tid >> 7;
  const int lane = tid & 63;
  const int n0 = blockIdx.x * TPB;

  __shared__ float4 h1T[128];
  __shared__ float4 part[3][128];
  __shared__ float4 kpart[8][32];
  __shared__ float4 kdT[32];
  __shared__ float4 kupart[256];
  __shared__ float4 rtmp[2];

  if (blockIdx.x == 0) {  // zero accumulators for later kernels
    for (int i = tid; i < 32 * 256; i += 512) ctx[i] = 0.f;
    ksum[tid] = 0.f;
    if (tid < 256) cnt[tid] = 0;
  }

  // rmsnorm1
  float xv[4];
  if (tid < 128) {
    float v[4];
#pragma unroll
    for (int t = 0; t < 4; t++) { xv[t] = x[(n0 + t) * Dd + j]; v[t] = xv[t] * xv[t]; }
#pragma unroll
    for (int o = 32; o > 0; o >>= 1) {
#pragma unroll
      for (int t = 0; t < 4; t++) v[t] += __shfl_xor(v[t], o, 64);
    }
    if (lane == 0) rtmp[tid >> 6] = make_float4(v[0], v[1], v[2], v[3]);
  }
  __syncthreads();
  if (tid < 128) {
    float g1j = g1[j];
#pragma unroll
    for (int t = 0; t < 4; t++) {
      float ss = ((const float*)&rtmp[0])[t] + ((const float*)&rtmp[1])[t];
      ((float*)&h1T[j])[t] = g1j * xv[t] * rsqrtf(ss * (1.f / 128.f) + EPSF);
    }
  }
  __syncthreads();

  // q GEMV, K-split-4
  {
    float a0 = 0, a1 = 0, a2 = 0, a3 = 0;
    const float* Wp = qW + (g * 32) * Dd + j;
#pragma unroll 16
    for (int i = 0; i < 32; i++) {
      float4 h4 = h1T[g * 32 + i];
      float w = Wp[i * Dd];
      a0 += h4.x * w; a1 += h4.y * w; a2 += h4.z * w; a3 += h4.w * w;
    }
    if (g) part[g - 1][j] = make_float4(a0, a1, a2, a3);
    __syncthreads();
    if (g == 0) {
      float4 p0 = part[0][j], p1 = part[1][j], p2 = part[2][j];
      float bb = qb[j];
      qbuf[(n0 + 0) * Dd + j] = elu1(a0 + p0.x + p1.x + p2.x + bb);
      qbuf[(n0 + 1) * Dd + j] = elu1(a1 + p0.y + p1.y + p2.y + bb);
      qbuf[(n0 + 2) * Dd + j] = elu1(a2 + p0.z + p1.z + p2.z + bb);
      qbuf[(n0 + 3) * Dd + j] = elu1(a3 + p0.w + p1.w + p2.w + bb);
    }
    __syncthreads();
  }

  // kd GEMV: 32 cols x 8 K-splits (tid<256)
  if (tid < 256) {
    int col = tid & 31, ksp = tid >> 5;
    float a0 = 0, a1 = 0, a2 = 0, a3 = 0;
    const float* Wp = kdW + (ksp * 16) * RR + col;
#pragma unroll
    for (int i = 0; i < 16; i++) {
      float4 h4 = h1T[ksp * 16 + i];
      float w = Wp[i * RR];
      a0 += h4.x * w; a1 += h4.y * w; a2 += h4.z * w; a3 += h4.w * w;
    }
    kpart[ksp][col] = make_float4(a0, a1, a2, a3);
  }
  __syncthreads();
  if (tid < 32) {
    float bb = kdb[tid];
    float s0 = bb, s1 = bb, s2 = bb, s3 = bb;
#pragma unroll
    for (int k = 0; k < 8; k++) {
      float4 p = kpart[k][tid];
      s0 += p.x; s1 += p.y; s2 += p.z; s3 += p.w;
    }
    kdT[tid] = make_float4(s0, s1, s2, s3);
  }
  __syncthreads();

  // ku GEMV: 256 cols, K=32 split 2
  {
    int col = tid & 255, kh = tid >> 8;
    float a0 = 0, a1 = 0, a2 = 0, a3 = 0;
    const float* Wp = kuW + (kh * 16) * 256 + col;
#pragma unroll
    for (int r = 0; r < 16; r++) {
      float4 k4 = kdT[kh * 16 + r];
      float w = Wp[r * 256];
      a0 += k4.x * w; a1 += k4.y * w; a2 += k4.z * w; a3 += k4.w * w;
    }
    if (kh) kupart[col] = make_float4(a0, a1, a2, a3);
    __syncthreads();
    if (!kh) {
      float4 p = kupart[col];
      float bb = kub[col];
      bool isk = (col & 31) < 16;
      float v0 = a0 + p.x + bb, v1 = a1 + p.y + bb, v2 = a2 + p.z + bb, v3 = a3 + p.w + bb;
      kvbuf[(n0 + 0) * 256 + col] = isk ? elu1(v0) : v0;
      kvbuf[(n0 + 1) * 256 + col] = isk ? elu1(v1) : v1;
      kvbuf[(n0 + 2) * 256 + col] = isk ? elu1(v2) : v2;
      kvbuf[(n0 + 3) * 256 + col] = isk ? elu1(v3) : v3;
    }
  }
}

// ===== k_ctx: blocks 0..255 ctx accumulate; 256..319 oR; 320 bR =============
__global__ __launch_bounds__(256) void k_ctx(const float* __restrict__ kv,
                                             float* __restrict__ ctx,
                                             float* __restrict__ ksum,
                                             const float* __restrict__ oW,
                                             const float* __restrict__ ob,
                                             const float* __restrict__ rot,
                                             float* __restrict__ oR,
                                             float* __restrict__ bR) {
  const int blk = blockIdx.x;
  const int tid = threadIdx.x;
  if (blk < 256) {
    const int bh = blk >> 3, c = blk & 7;
    const int b = bh >> 3, h = bh & 7;
    const int d = tid >> 4, e = tid & 15;
    __shared__ float sh[64 * 32];
#pragma unroll
    for (int r = 0; r < 8; r++) {
      int lin = r * 256 + tid;
      int tok = lin >> 5, off = lin & 31;
      sh[lin] = kv[((b * TT + c * 64 + tok) * 256) + h * 32 + off];
    }
    __syncthreads();
    float acc = 0.f, ks = 0.f;
#pragma unroll 4
    for (int t = 0; t < 64; t++) {
      float kk = sh[t * 32 + d];
      acc += kk * sh[t * 32 + 16 + e];
      ks += kk;
    }
    atomicAdd(&ctx[bh * 256 + d * 16 + e], acc);
    if (e == 0) atomicAdd(&ksum[bh * 16 + d], ks);
  } else if (blk < 320) {               // oR = oW @ rot : one elem per thread
    int idx = (blk - 256) * 256 + tid;
    int row = idx >> 7, col = idx & 127;
    const float* ow = oW + row * 128;
    float acc = 0.f;
#pragma unroll 8
    for (int k = 0; k < 128; k++) acc += ow[k] * rot[k * 128 + col];
    oR[row * 128 + col] = acc;
  } else {                              // bR = ob @ rot
    if (tid < 128) {
      float acc = 0.f;
#pragma unroll 8
      for (int k = 0; k < 128; k++) acc += ob[k] * rot[k * 128 + tid];
      bR[tid] = acc;
    }
  }
}

// ===== k_mid: attn -> oR(+quant) -> s1s2(+res) -> rms2||gate -> top2+scatter
__global__ __launch_bounds__(512) void k_mid(
    const float* __restrict__ x, const float* __restrict__ qbuf,
    const float* __restrict__ ctx, const float* __restrict__ ksum,
    const float* __restrict__ oR, const float* __restrict__ bR,
    const float* __restrict__ tqs,
    const float* __restrict__ s1W, const float* __restrict__ s1b,
    const float* __restrict__ s2W, const float* __restrict__ s2b,
    const float* __restrict__ g2, const float* __restrict__ gateW,
    const float* __restrict__ gateb,
    float* __restrict__ xnbuf, float* __restrict__ h2buf,
    float* __restrict__ gw, int* __restrict__ tokslot,
    int* __restrict__ slottok, int* __restrict__ cnt) {
  const int tid = threadIdx.x;
  const int j = tid & 127, g = tid >> 7;
  const int lane = tid & 63;
  const int n0 = blockIdx.x * TPB;
  const int b = n0 >> 9;

  __shared__ float4 bufA[128], bufB[128];
  __shared__ float4 part[3][128];
  __shared__ float4 gpart[256];
  __shared__ float4 rtmp[2];
  __shared__ float wvS[4][4]; __shared__ int wiS[4][4];
  __shared__ float zS[4][4];

  float xres[4];
  if (tid < 128) {
#pragma unroll
    for (int t = 0; t < 4; t++) xres[t] = x[(n0 + t) * Dd + j];
  }

  // phase 1: load q token-transposed
  ((float*)&bufA[j])[g] = qbuf[(n0 + g) * Dd + j];
  __syncthreads();

  // phase 2: attention apply -> bufB (tid<128, K=16)
  if (tid < 128) {
    int h = j >> 4, e = j & 15;
    const float* cpt = ctx + (b * NH + h) * 256;
    const float* kpt = ksum + (b * NH + h) * 16;
    float num[4] = {0, 0, 0, 0}, den[4] = {0, 0, 0, 0};
#pragma unroll
    for (int d = 0; d < 16; d++) {
      float cx = cpt[d * 16 + e], ks = kpt[d];
      float4 q4 = bufA[h * 16 + d];
      num[0] += q4.x * cx; num[1] += q4.y * cx; num[2] += q4.z * cx; num[3] += q4.w * cx;
      den[0] += q4.x * ks; den[1] += q4.y * ks; den[2] += q4.z * ks; den[3] += q4.w * ks;
    }
#pragma unroll
    for (int t = 0; t < 4; t++) ((float*)&bufB[j])[t] = num[t] / (den[t] + EPSF);
  }
  __syncthreads();

  // phase 3: z = bufB @ oR + bR; quant: clamp(z,±mag)*tqs -> bufA
  {
    float a0 = 0, a1 = 0, a2 = 0, a3 = 0;
    const float* Wp = oR + (g * 32) * Dd + j;
#pragma unroll 16
    for (int i = 0; i < 32; i++) {
      float4 h4 = bufB[g * 32 + i];
      float w = Wp[i * Dd];
      a0 += h4.x * w; a1 += h4.y * w; a2 += h4.z * w; a3 += h4.w * w;
    }
    if (g) part[g - 1][j] = make_float4(a0, a1, a2, a3);
    __syncthreads();
    float tot[4];
    if (g == 0) {
      float4 p0 = part[0][j], p1 = part[1][j], p2 = part[2][j];
      float bb = bR[j];
      tot[0] = a0 + p0.x + p1.x + p2.x + bb; tot[1] = a1 + p0.y + p1.y + p2.y + bb;
      tot[2] = a2 + p0.z + p1.z + p2.z + bb; tot[3] = a3 + p0.w + p1.w + p2.w + bb;
      float v[4];
#pragma unroll
      for (int t = 0; t < 4; t++) v[t] = tot[t] * tot[t];
#pragma unroll
      for (int o = 32; o > 0; o >>= 1) {
#pragma unroll
        for (int t = 0; t < 4; t++) v[t] += __shfl_xor(v[t], o, 64);
      }
      if (lane == 0) rtmp[tid >> 6] = make_float4(v[0], v[1], v[2], v[3]);
    }
    __syncthreads();
    if (g == 0) {
      float scj = tqs[j];
#pragma unroll
      for (int t = 0; t < 4; t++) {
        float ss = ((const float*)&rtmp[0])[t] + ((const float*)&rtmp[1])[t];
        float mag = sqrtf(ss * (1.f / 128.f) + EPSF);
        float zc = fminf(fmaxf(tot[t], -mag), mag);
        ((float*)&bufA[j])[t] = zc * scj;
      }
    }
    __syncthreads();
  }

  // phase 4: s1/s2 dual GEMV on bufA -> xn (+res); bufB = g2*xn; rtmp=sumsq
  {
    float a0 = 0, a1 = 0, a2 = 0, a3 = 0;
    const float* Wp = (g < 2 ? s1W : s2W) + ((g & 1) * 64) * Dd + j;
#pragma unroll 16
    for (int i = 0; i < 64; i++) {
      float4 h4 = bufA[(g & 1) * 64 + i];
      float w = Wp[i * Dd];
      a0 += h4.x * w; a1 += h4.y * w; a2 += h4.z * w; a3 += h4.w * w;
    }
    if (g) part[g - 1][j] = make_float4(a0, a1, a2, a3);
    __syncthreads();
    if (g == 0) {
      float b1 = s1b[j], b2 = s2b[j];
      float4 p0 = part[0][j], p1 = part[1][j], p2 = part[2][j];
      float gv[4], uv[4], xn[4], v[4];
      gv[0] = a0 + p0.x + b1; gv[1] = a1 + p0.y + b1;
      gv[2] = a2 + p0.z + b1; gv[3] = a3 + p0.w + b1;
      uv[0] = p1.x + p2.x + b2; uv[1] = p1.y + p2.y + b2;
      uv[2] = p1.z + p2.z + b2; uv[3] = p1.w + p2.w + b2;
      float g2j = g2[j];
#pragma unroll
      for (int t = 0; t < 4; t++) {
        xn[t] = xres[t] + gv[t] * sigm(gv[t]) * uv[t];
        xnbuf[(n0 + t) * Dd + j] = xn[t];
        ((float*)&bufB[j])[t] = g2j * xn[t];   // pre-r2 h2
        v[t] = xn[t] * xn[t];
      }
#pragma unroll
      for (int o = 32; o > 0; o >>= 1) {
#pragma unroll
        for (int t = 0; t < 4; t++) v[t] += __shfl_xor(v[t], o, 64);
      }
      if (lane == 0) rtmp[tid >> 6] = make_float4(v[0], v[1], v[2], v[3]);
    }
    __syncthreads();
  }

  // phase 5: gate logits on bufB (K-split-2, 256 cols); r2 applied at epilogue
  float val[4];
  float r2[4];
  {
    int col = tid & 255, kh = tid >> 8;
    float a0 = 0, a1 = 0, a2 = 0, a3 = 0;
    const float* Wp = gateW + (kh * 64) * NE + col;
#pragma unroll 16
    for (int i = 0; i < 64; i++) {
      float4 h4 = bufB[kh * 64 + i];
      float w = Wp[i * NE];
      a0 += h4.x * w; a1 += h4.y * w; a2 += h4.z * w; a3 += h4.w * w;
    }
    if (kh) gpart[col] = make_float4(a0, a1, a2, a3);
    __syncthreads();
#pragma unroll
    for (int t = 0; t < 4; t++) {
      float ss = ((const float*)&rtmp[0])[t] + ((const float*)&rtmp[1])[t];
      r2[t] = rsqrtf(ss * (1.f / 128.f) + EPSF);
    }
    if (!kh) {
      float4 p = gpart[col];
      float bb = gateb[col];
      val[0] = (a0 + p.x) * r2[0] + bb; val[1] = (a1 + p.y) * r2[1] + bb;
      val[2] = (a2 + p.z) * r2[2] + bb; val[3] = (a3 + p.w) * r2[3] + bb;
    }
    if (tid < 128) {  // h2 = r2 * g2 * xn
#pragma unroll
      for (int t = 0; t < 4; t++)
        h2buf[(n0 + t) * Dd + j] = ((const float*)&bufB[j])[t] * r2[t];
    }
  }
  __syncthreads();

  // top-2 over 256 logits (tid<256)
  float m1[4]; int i1[4];
  {
    if (tid < 256) {
      float bv[4]; int bi[4];
#pragma unroll
      for (int t = 0; t < 4; t++) { bv[t] = val[t]; bi[t] = tid; }
#pragma unroll
      for (int o = 32; o > 0; o >>= 1) {
#pragma unroll
        for (int t = 0; t < 4; t++) {
          float wv = __shfl_xor(bv[t], o, 64);
          int wi = __shfl_xor(bi[t], o, 64);
          if (wv > bv[t] || (wv == bv[t] && wi < bi[t])) { bv[t] = wv; bi[t] = wi; }
        }
      }
      if (lane == 0) {
#pragma unroll
        for (int t = 0; t < 4; t++) { wvS[tid >> 6][t] = bv[t]; wiS[tid >> 6][t] = bi[t]; }
      }
    }
    __syncthreads();
    if (tid < 256) {
#pragma unroll
      for (int t = 0; t < 4; t++) {
        m1[t] = wvS[0][t]; i1[t] = wiS[0][t];
#pragma unroll
        for (int w = 1; w < 4; w++) {
          float cv = wvS[w][t]; int ci = wiS[w][t];
          if (cv > m1[t] || (cv == m1[t] && ci < i1[t])) { m1[t] = cv; i1[t] = ci; }
        }
      }
    }
    __syncthreads();
  }
  float m2[4]; int i2[4];
  {
    if (tid < 256) {
      float bv[4]; int bi[4];
#pragma unroll
      for (int t = 0; t < 4; t++) {
        bv[t] = (tid == i1[t]) ? -INFINITY : val[t];
        bi[t] = tid;
      }
#pragma unroll
      for (int o = 32; o > 0; o >>= 1) {
#pragma unroll
        for (int t = 0; t < 4; t++) {
          float wv = __shfl_xor(bv[t], o, 64);
          int wi = __shfl_xor(bi[t], o, 64);
          if (wv > bv[t] || (wv == bv[t] && wi < bi[t])) { bv[t] = wv; bi[t] = wi; }
        }
      }
      if (lane == 0) {
#pragma unroll
        for (int t = 0; t < 4; t++) { wvS[tid >> 6][t] = bv[t]; wiS[tid >> 6][t] = bi[t]; }
      }
    }
    __syncthreads();
    if (tid < 256) {
#pragma unroll
      for (int t = 0; t < 4; t++) {
        m2[t] = wvS[0][t]; i2[t] = wiS[0][t];
#pragma unroll
        for (int w = 1; w < 4; w++) {
          float cv = wvS[w][t]; int ci = wiS[w][t];
          if (cv > m2[t] || (cv == m2[t] && ci < i2[t])) { m2[t] = cv; i2[t] = ci; }
        }
      }
    }
    __syncthreads();
  }
  {
    if (tid < 256) {
      float v[4];
#pragma unroll
      for (int t = 0; t < 4; t++) v[t] = expf(val[t] - m1[t]);
#pragma unroll
      for (int o = 32; o > 0; o >>= 1) {
#pragma unroll
        for (int t = 0; t < 4; t++) v[t] += __shfl_xor(v[t], o, 64);
      }
      if (lane == 0) {
#pragma unroll
        for (int t = 0; t < 4; t++) zS[tid >> 6][t] = v[t];
      }
    }
    __syncthreads();
  }
  if (tid < 4) {
    int t = tid, tok = n0 + t;
    float Z = zS[0][t] + zS[1][t] + zS[2][t] + zS[3][t];
    float p1 = 1.f / Z;
    float p2 = expf(m2[t] - m1[t]) / Z;
    float s = p1 + p2 + EPSF;
    int e1 = i1[t], e2 = i2[t];
    int s1 = atomicAdd(&cnt[e1], 1); if (s1 > SLOTS - 1) s1 = SLOTS - 1;
    int s2 = atomicAdd(&cnt[e2], 1); if (s2 > SLOTS - 1) s2 = SLOTS - 1;
    int sl1 = e1 * SLOTS + s1, sl2 = e2 * SLOTS + s2;
    slottok[sl1] = tok; slottok[sl2] = tok;
    tokslot[tok * 2] = sl1; tokslot[tok * 2 + 1] = sl2;
    gw[tok * 2] = p1 / s; gw[tok * 2 + 1] = p2 / s;
  }
}

// ===== k_exp: one block per expert, fixed slot base ==========================
__global__ __launch_bounds__(512) void k_exp(const float* __restrict__ h2buf,
                                             const int* __restrict__ slottok,
                                             const int* __restrict__ cnt,
                                             const float* __restrict__ expW,
                                             float* __restrict__ ybuf) {
  const int e = blockIdx.x;
  int n = cnt[e]; if (n > SLOTS) n = SLOTS;
  if (n == 0) return;
  const int base = e * SLOTS;
  const int tid = threadIdx.x;
  const int j = tid & 127, g = tid >> 7;
  __shared__ __align__(16) float hT[128 * 20];
  const float* Wp = expW + (size_t)e * Dd * Dd + j;
  for (int t0 = 0; t0 < n; t0 += 16) {
    int m = n - t0; if (m > 16) m = 16;
    __syncthreads();
    for (int tt = g; tt < m; tt += 4) {
      int tok = slottok[base + t0 + tt];
      hT[j * 20 + tt] = h2buf[tok * Dd + j];
    }
    __syncthreads();
    float acc[4] = {0, 0, 0, 0};
#pragma unroll 8
    for (int i = 0; i < 128; i++) {
      float w = Wp[i * Dd];
      float4 h4 = *(const float4*)&hT[i * 20 + g * 4];
      acc[0] += h4.x * w; acc[1] += h4.y * w; acc[2] += h4.z * w; acc[3] += h4.w * w;
    }
#pragma unroll
    for (int k = 0; k < 4; k++) {
      int tt = g * 4 + k;
      if (tt < m) ybuf[(size_t)(base + t0 + tt) * Dd + j] = acc[k];
    }
  }
}

// ===== k_post ================================================================
__global__ __launch_bounds__(512) void k_post(
    const float* __restrict__ xnbuf, const float* __restrict__ ybuf,
    const int* __restrict__ tokslot, const float* __restrict__ gw,
    const float* __restrict__ m1W, const float* __restrict__ m1b,
    const float* __restrict__ m2W, const float* __restrict__ m2b,
    float* __restrict__ out) {
  const int tid = threadIdx.x;
  const int j = tid & 127, g = tid >> 7;
  const int lane = tid & 63;
  const int n0 = blockIdx.x * TPB;

  __shared__ float4 y1T[128], y2T[128], inT[128], sT[128];
  __shared__ float4 part[3][128];
  __shared__ float4 rtmp[2];
  __shared__ int sSlot[4][2];
  __shared__ float sWt[4][2];

  if (tid < 4) {
    sSlot[tid][0] = tokslot[(n0 + tid) * 2];
    sSlot[tid][1] = tokslot[(n0 + tid) * 2 + 1];
    sWt[tid][0] = gw[(n0 + tid) * 2];
    sWt[tid][1] = gw[(n0 + tid) * 2 + 1];
  }
  __syncthreads();

  {
    float y1 = ybuf[(size_t)sSlot[g][0] * Dd + j];
    float y2 = ybuf[(size_t)sSlot[g][1] * Dd + j];
    ((float*)&y1T[j])[g] = y1;
    ((float*)&y2T[j])[g] = y2;
    ((float*)&inT[j])[g] = sWt[g][0] * y1 + sWt[g][1] * y2;
  }
  __syncthreads();

  {
    float a0 = 0, a1 = 0, a2 = 0, a3 = 0;
    const float* Wp = (g < 2 ? m1W : m2W) + ((g & 1) * 64) * Dd + j;
#pragma unroll 16
    for (int i = 0; i < 64; i++) {
      float4 h4 = inT[(g & 1) * 64 + i];
      float w = Wp[i * Dd];
      a0 += h4.x * w; a1 += h4.y * w; a2 += h4.z * w; a3 += h4.w * w;
    }
    if (g) part[g - 1][j] = make_float4(a0, a1, a2, a3);
    __syncthreads();
    if (g == 0) {
      float b1 = m1b[j], b2 = m2b[j];
      float4 p0 = part[0][j], p1 = part[1][j], p2 = part[2][j];
      float gv[4], uv[4];
      gv[0] = a0 + p0.x + b1; gv[1] = a1 + p0.y + b1;
      gv[2] = a2 + p0.z + b1; gv[3] = a3 + p0.w + b1;
      uv[0] = p1.x + p2.x + b2; uv[1] = p1.y + p2.y + b2;
      uv[2] = p1.z + p2.z + b2; uv[3] = p1.w + p2.w + b2;
#pragma unroll
      for (int t = 0; t < 4; t++) {
        float sv = gv[t] * sigm(gv[t]) * uv[t];
        ((float*)&sT[j])[t] = sv;
        out[(n0 + t) * Dd + j] = xnbuf[(n0 + t) * Dd + j] + sv;
      }
    }
    __syncthreads();
  }

  if (tid < 128) {
    float v[4];
#pragma unroll
    for (int t = 0; t < 4; t++) {
      float sv = ((const float*)&sT[j])[t];
      float d1 = ((const float*)&y1T[j])[t] - sv;
      float d2 = ((const float*)&y2T[j])[t] - sv;
      v[t] = sWt[t][0] * d1 * d1 + sWt[t][1] * d2 * d2;
    }
#pragma unroll
    for (int o = 32; o > 0; o >>= 1) {
#pragma unroll
      for (int t = 0; t < 4; t++) v[t] += __shfl_xor(v[t], o, 64);
    }
    if (lane == 0) rtmp[tid >> 6] = make_float4(v[0], v[1], v[2], v[3]);
  }
  __syncthreads();
  if (tid < 4) {
    float s = ((const float*)&rtmp[0])[tid] + ((const float*)&rtmp[1])[tid];
    out[NTOK * Dd + n0 + tid] = expf(-s * (1.f / 128.f));
  }
}

extern "C" void kernel_launch(void* const* d_in, const int* in_sizes, int n_in,
                              void* d_out, int out_size, void* d_ws, size_t ws_size,
                              hipStream_t stream) {
  const float* x   = (const float*)d_in[0];
  const float* g1  = (const float*)d_in[1];
  const float* qW  = (const float*)d_in[2];
  const float* qb  = (const float*)d_in[3];
  const float* kdW = (const float*)d_in[4];
  const float* kdb = (const float*)d_in[5];
  const float* kuW = (const float*)d_in[6];
  const float* kub = (const float*)d_in[7];
  const float* oW  = (const float*)d_in[8];
  const float* ob  = (const float*)d_in[9];
  const float* rot = (const float*)d_in[10];
  const float* tqs = (const float*)d_in[11];
  const float* s1W = (const float*)d_in[12];
  const float* s1b = (const float*)d_in[13];
  const float* s2W = (const float*)d_in[14];
  const float* s2b = (const float*)d_in[15];
  const float* g2  = (const float*)d_in[16];
  const float* gW  = (const float*)d_in[17];
  const float* gb  = (const float*)d_in[18];
  const float* eW  = (const float*)d_in[19];
  const float* m1W = (const float*)d_in[20];
  const float* m1b = (const float*)d_in[21];
  const float* m2W = (const float*)d_in[22];
  const float* m2b = (const float*)d_in[23];
  float* out = (float*)d_out;
  float* ws  = (float*)d_ws;

  float* qbuf   = ws;                     // 262144
  float* kvbuf  = ws + 262144;            // 524288
  float* ctx    = ws + 786432;            // 8192
  float* ksum   = ws + 794624;            // 512
  float* h2buf  = ws + 795136;            // 262144
  float* xnbuf  = ws + 1057280;           // 262144
  float* gw     = ws + 1319424;           // 4096
  float* oRb    = ws + 1323520;           // 16384
  float* bRb    = ws + 1339904;           // 128
  int*   cnt     = (int*)(ws + 1373056);  // 256
  int*   tokslot = (int*)(ws + 1373312);  // 4096
  int*   slottok = (int*)(ws + 1377408);  // 65536
  float* ybuf   = ws + 1442944;           // 256*256*128

  k_pre<<<NTOK / TPB, 512, 0, stream>>>(x, g1, qW, qb, kdW, kdb, kuW, kub,
                                        qbuf, kvbuf, ctx, ksum, cnt);
  k_ctx<<<321, 256, 0, stream>>>(kvbuf, ctx, ksum, oW, ob, rot, oRb, bRb);
  k_mid<<<NTOK / TPB, 512, 0, stream>>>(x, qbuf, ctx, ksum, oRb, bRb, tqs,
                                        s1W, s1b, s2W, s2b, g2, gW, gb,
                                        xnbuf, h2buf, gw, tokslot, slottok, cnt);
  k_exp<<<NE, 512, 0, stream>>>(h2buf, slottok, cnt, eW, ybuf);
  k_post<<<NTOK / TPB, 512, 0, stream>>>(xnbuf, ybuf, tokslot, gw,
                                         m1W, m1b, m2W, m2b, out);
}